// Round 4
// baseline (4916.533 us; speedup 1.0000x reference)
//
#include <hip/hip_runtime.h>

// ---------------------------------------------------------------------------
// SimpleGRU on MI355X (gfx950). Round 4: grid-resident recurrence, de-serialized.
//   Round-3 failure modes (from counters):
//     - VGPR=156 -> compiler refused 192-VGPR B-frag residency (spill/reload).
//     - atomic-load->LDS staging serialized (vmcnt(0) per 8B) ~4.6us/step.
//   Now: W_hh slice lives in LDS in exact B-fragment order (conflict-free
//   ds_read_b128); h A-fragments load direct global->VGPR with sc0 sc1
//   (coherent, pipelined, one waitcnt join); per-WAVE flags -> zero per-step
//   barriers. 32 blocks x 256 thr, 1 block/CU, lockstep via 128 flags.
// ws: xg bf16 [512][1536][64] (100,663,296 B) | hbuf f16 [2][64][512] (131,072 B)
//     | flags int[128]
// ---------------------------------------------------------------------------

typedef unsigned short ushort_t;
typedef short short8      __attribute__((ext_vector_type(8)));
typedef float floatx4     __attribute__((ext_vector_type(4)));
typedef unsigned short ushort4v __attribute__((ext_vector_type(4)));
typedef _Float16 half8    __attribute__((ext_vector_type(8)));

#define SEQL 512
#define BATCH 64
#define EMBD 256
#define HID 512
#define G3 1536
#define NOUT 5
#define NBLK 32            // hidden-split blocks, 1 per CU, co-resident
#define NFLAG 128          // per-wave flags: 32 blocks x 4 waves

__device__ __forceinline__ float bf2f(ushort_t v){
  union { unsigned u; float f; } x; x.u = ((unsigned)v) << 16; return x.f;
}
__device__ __forceinline__ ushort_t f2bf(float f){
  unsigned u = __float_as_uint(f);
  return (ushort_t)((u + 0x7FFFu + ((u >> 16) & 1u)) >> 16);
}
__device__ __forceinline__ float sigm(float x){
  x = fminf(fmaxf(x, -20.f), 20.f);
  return 1.f / (1.f + __expf(-x));
}
__device__ __forceinline__ float tanh_c(float x){
  x = fminf(fmaxf(x, -10.f), 10.f);
  float e = __expf(2.f * x);
  return (e - 1.f) / (e + 1.f);
}

// --- K0: zero hbuf (2*64*512 f16 = 128KB) + flags(128) ---
__global__ __launch_bounds__(256) void gru_init(unsigned long long* __restrict__ hbuf8,
                                                int* __restrict__ flags){
  int i = blockIdx.x * 256 + threadIdx.x;       // grid 64 -> 16384 thr * 8B = 128KB
  hbuf8[i] = 0ull;
  if (blockIdx.x == 0 && threadIdx.x < NFLAG) flags[threadIdx.x] = 0;
}

// --- K1: x_gates = emb[seq] @ w_ih^T + b_ih, bf16, layout [s][1536][64] ---
#define LDSIDX2(row, chunk) (((row) << 7) + ((((chunk) ^ ((row) & 7))) << 3))
__global__ __launch_bounds__(256) void gru_xgates(
    const int* __restrict__ seq, const float* __restrict__ emb,
    const float* __restrict__ w_ih, const float* __restrict__ b_ih,
    ushort_t* __restrict__ xg)
{
  __shared__ __align__(16) short lA[64 * 128];
  __shared__ __align__(16) short lB[64 * 128];
  const int tid   = threadIdx.x;
  const int sIdx  = blockIdx.x;
  const int nBase = blockIdx.y * 64;
  const int w    = tid >> 6;
  const int l    = tid & 63;
  const int l15  = l & 15;
  const int quad = l >> 4;
  floatx4 acc[4] = {};

  #pragma unroll
  for (int kp = 0; kp < 2; ++kp){
    __syncthreads();
    #pragma unroll
    for (int i = 0; i < 4; ++i){
      int lin = i * 256 + tid;
      int row = lin >> 4;
      int kc  = lin & 15;
      int kbase = kp * 128 + kc * 8;
      int token = seq[(sIdx << 6) + row];
      const float* srcA = emb  + (size_t)token * EMBD + kbase;
      const float* srcB = w_ih + (size_t)(nBase + row) * EMBD + kbase;
      floatx4 a0 = *(const floatx4*)(srcA);
      floatx4 a1 = *(const floatx4*)(srcA + 4);
      floatx4 b0 = *(const floatx4*)(srcB);
      floatx4 b1 = *(const floatx4*)(srcB + 4);
      short8 pa, pb;
      #pragma unroll
      for (int j = 0; j < 4; ++j){
        pa[j]     = (short)f2bf(a0[j]);
        pa[j + 4] = (short)f2bf(a1[j]);
        pb[j]     = (short)f2bf(b0[j]);
        pb[j + 4] = (short)f2bf(b1[j]);
      }
      *(short8*)&lA[LDSIDX2(row, kc)] = pa;
      *(short8*)&lB[LDSIDX2(row, kc)] = pb;
    }
    __syncthreads();
    #pragma unroll
    for (int kc = 0; kc < 4; ++kc){
      int chunk = kc * 4 + quad;
      short8 a = *(const short8*)&lA[LDSIDX2(w * 16 + l15, chunk)];
      #pragma unroll
      for (int s = 0; s < 4; ++s){
        short8 bf = *(const short8*)&lB[LDSIDX2(s * 16 + l15, chunk)];
        acc[s] = __builtin_amdgcn_mfma_f32_16x16x32_bf16(a, bf, acc[s], 0, 0, 0);
      }
    }
  }
  // C/D: col=lane&15 (g within 16), row=quad*4+reg (batch). Store b-fastest.
  #pragma unroll
  for (int s = 0; s < 4; ++s){
    int g = nBase + s * 16 + l15;
    float bias = b_ih[g];
    ushort4v pk;
    #pragma unroll
    for (int r = 0; r < 4; ++r) pk[r] = f2bf(acc[s][r] + bias);
    *(ushort4v*)(xg + ((size_t)sIdx * G3 + g) * BATCH + (w * 16 + quad * 4)) = pk;
  }
}

// --- K2: grid-resident recurrence. 32 blocks x 256 threads (1 block/CU). ---
__global__ __launch_bounds__(256, 1) void gru_rec(
    const ushort_t* __restrict__ xg, const float* __restrict__ whh,
    const float* __restrict__ bhh, const int* __restrict__ lengths,
    _Float16* __restrict__ hbuf, int* __restrict__ flags)
{
  // W_hh B-fragments, exact lane order: frag p=(G*16+ks), lane l -> 16B chunk.
  __shared__ __align__(16) _Float16 wlds[48 * 64 * 8];   // 49,152 B
  const int g    = blockIdx.x;          // hidden slice [g*16, g*16+16)
  const int tid  = threadIdx.x;
  const int w    = tid >> 6;
  const int l    = tid & 63;
  const int l15  = l & 15;
  const int quad = l >> 4;
  const int j    = g * 16 + l15;        // this lane's hidden unit
  const int bbase = w * 16 + quad * 4;  // this lane's 4 batches

  // --- setup: convert this block's 48 W_hh rows f32->f16 into B-frag layout ---
  #pragma unroll
  for (int i = 0; i < 12; ++i){
    int p  = i * 4 + w;                 // 0..47
    int G  = p >> 4;                    // gate (0=r,1=z,2=n)
    int ks = p & 15;                    // K-step
    const float* src = whh + (size_t)(G * HID + j) * HID + ks * 32 + quad * 8;
    floatx4 f0 = *(const floatx4*)(src);
    floatx4 f1 = *(const floatx4*)(src + 4);
    half8 hv;
    #pragma unroll
    for (int q = 0; q < 4; ++q){ hv[q] = (_Float16)f0[q]; hv[q + 4] = (_Float16)f1[q]; }
    *(half8*)&wlds[((size_t)p * 64 + l) * 8] = hv;
  }
  const float bhR = bhh[j], bhZ = bhh[HID + j], bhN = bhh[2 * HID + j];
  int   len[4];
  float h[4];
  #pragma unroll
  for (int r = 0; r < 4; ++r){ len[r] = lengths[bbase + r]; h[r] = 0.f; }
  const int Lmax = lengths[0];          // sorted descending
  __syncthreads();                      // wlds ready (only barrier besides none)

  const int myflag = w * NBLK + g;      // per-wave flag

  for (int t = 0; t < Lmax; ++t){
    // 1) xg prefetch (independent of h) — issue before the spin
    const ushort_t* xt = xg + (size_t)t * G3 * BATCH;
    ushort4v xR = *(const ushort4v*)(xt + (size_t)(        j) * BATCH + bbase);
    ushort4v xZ = *(const ushort4v*)(xt + (size_t)(HID   + j) * BATCH + bbase);
    ushort4v xN = *(const ushort4v*)(xt + (size_t)(2*HID + j) * BATCH + bbase);

    // 2) per-wave spin: all 128 wave-flags >= t (lane l polls flags[l], flags[l+64])
    if (t > 0){
      while (true){
        int f0 = __hip_atomic_load(flags + l,      __ATOMIC_RELAXED, __HIP_MEMORY_SCOPE_AGENT);
        int f1 = __hip_atomic_load(flags + 64 + l, __ATOMIC_RELAXED, __HIP_MEMORY_SCOPE_AGENT);
        if (__all(f0 >= t && f1 >= t)) break;
      }
    }

    // 3) A-fragments: 16 coherent 16B loads global->VGPR (pipelined), one join
    const _Float16* hsrc = hbuf + (size_t)(t & 1) * BATCH * HID
                         + (size_t)(w * 16 + l15) * HID + quad * 8;
    half8 aF[16];
    #pragma unroll
    for (int ks = 0; ks < 16; ++ks){
      const _Float16* pa = hsrc + ks * 32;
      asm volatile("global_load_dwordx4 %0, %1, off sc0 sc1"
                   : "=v"(aF[ks]) : "v"(pa) : "memory");
    }
    asm volatile("s_waitcnt vmcnt(0)"
                 : "+v"(aF[0]),  "+v"(aF[1]),  "+v"(aF[2]),  "+v"(aF[3]),
                   "+v"(aF[4]),  "+v"(aF[5]),  "+v"(aF[6]),  "+v"(aF[7]),
                   "+v"(aF[8]),  "+v"(aF[9]),  "+v"(aF[10]), "+v"(aF[11]),
                   "+v"(aF[12]), "+v"(aF[13]), "+v"(aF[14]), "+v"(aF[15])
                 :: "memory");

    // 4) MFMA: M=64(batch, this wave's 16) x N=48(gates) x K=512
    floatx4 aR = {0.f,0.f,0.f,0.f}, aZ = {0.f,0.f,0.f,0.f}, aN = {0.f,0.f,0.f,0.f};
    #pragma unroll
    for (int ks = 0; ks < 16; ++ks){
      half8 a  = aF[ks];
      half8 b0 = *(const half8*)&wlds[((size_t)(0 * 16 + ks) * 64 + l) * 8];
      half8 b1 = *(const half8*)&wlds[((size_t)(1 * 16 + ks) * 64 + l) * 8];
      half8 b2 = *(const half8*)&wlds[((size_t)(2 * 16 + ks) * 64 + l) * 8];
      aR = __builtin_amdgcn_mfma_f32_16x16x32_f16(a, b0, aR, 0, 0, 0);
      aZ = __builtin_amdgcn_mfma_f32_16x16x32_f16(a, b1, aZ, 0, 0, 0);
      aN = __builtin_amdgcn_mfma_f32_16x16x32_f16(a, b2, aN, 0, 0, 0);
    }

    // 5) gates + h update (f32 carry) + coherent f16 stores
    _Float16* hdst = hbuf + (size_t)((t + 1) & 1) * BATCH * HID;
    #pragma unroll
    for (int r = 0; r < 4; ++r){
      float rr = sigm(bf2f(xR[r]) + aR[r] + bhR);
      float zz = sigm(bf2f(xZ[r]) + aZ[r] + bhZ);
      float nn = tanh_c(bf2f(xN[r]) + rr * (aN[r] + bhN));
      float hn = (1.f - zz) * nn + zz * h[r];
      h[r] = (t < len[r]) ? hn : h[r];
      union { _Float16 hf; unsigned short us; } cv; cv.hf = (_Float16)h[r];
      __hip_atomic_store((unsigned short*)(hdst + (size_t)(bbase + r) * HID + j),
                         cv.us, __ATOMIC_RELAXED, __HIP_MEMORY_SCOPE_AGENT);
    }
    // 6) per-wave publish: own stores acked -> own flag. No block barrier.
    asm volatile("s_waitcnt vmcnt(0) lgkmcnt(0)" ::: "memory");
    if (l == 0)
      __hip_atomic_store(flags + myflag, t + 1, __ATOMIC_RELEASE, __HIP_MEMORY_SCOPE_AGENT);
  }
}

// --- K3: logits + log_softmax. 64 blocks x 64 threads (1 wave). ---
__global__ __launch_bounds__(64) void gru_out(
    const _Float16* __restrict__ hbuf, const int* __restrict__ lengths,
    const float* __restrict__ wout, const float* __restrict__ bout,
    float* __restrict__ out)
{
  const int b = blockIdx.x, l = threadIdx.x;
  const _Float16* h = hbuf + (size_t)(lengths[0] & 1) * BATCH * HID + (size_t)b * HID;
  half8 hv = *(const half8*)(h + l * 8);
  float p[NOUT];
  #pragma unroll
  for (int o = 0; o < NOUT; ++o){
    const float* wr = wout + o * HID + l * 8;
    float a = 0.f;
    #pragma unroll
    for (int i = 0; i < 8; ++i) a += wr[i] * (float)hv[i];
    #pragma unroll
    for (int d = 32; d >= 1; d >>= 1) a += __shfl_down(a, d, 64);
    p[o] = a;
  }
  if (l == 0){
    float lg[NOUT], m = -1e30f;
    #pragma unroll
    for (int o = 0; o < NOUT; ++o){
      float v = p[o] + bout[o];
      if (!(v == v)) v = -1.0f;
      lg[o] = v; m = fmaxf(m, v);
    }
    float ssum = 0.f;
    #pragma unroll
    for (int o = 0; o < NOUT; ++o) ssum += __expf(lg[o] - m);
    float ls = __logf(ssum);
    #pragma unroll
    for (int o = 0; o < NOUT; ++o) out[b * NOUT + o] = lg[o] - m - ls;
  }
}

extern "C" void kernel_launch(void* const* d_in, const int* in_sizes, int n_in,
                              void* d_out, int out_size, void* d_ws, size_t ws_size,
                              hipStream_t stream) {
  (void)in_sizes; (void)n_in; (void)out_size; (void)ws_size;
  const int*   seq     = (const int*)d_in[0];
  const int*   lengths = (const int*)d_in[1];
  const float* emb     = (const float*)d_in[2];
  const float* w_ih    = (const float*)d_in[3];
  const float* w_hh    = (const float*)d_in[4];
  const float* b_ih    = (const float*)d_in[5];
  const float* b_hh    = (const float*)d_in[6];
  const float* w_out   = (const float*)d_in[7];
  const float* b_out   = (const float*)d_in[8];
  float*       outp    = (float*)d_out;

  char* ws = (char*)d_ws;
  ushort_t* xg    = (ushort_t*)ws;                               // 100,663,296 B
  _Float16* hbuf  = (_Float16*)(ws + 100663296);                 //     131,072 B
  int*      flags = (int*)     (ws + 100663296 + 131072);        //         512 B

  gru_init<<<64, 256, 0, stream>>>((unsigned long long*)hbuf, flags);
  dim3 g1(SEQL, G3 / 64);
  gru_xgates<<<g1, 256, 0, stream>>>(seq, emb, w_ih, b_ih, xg);
  gru_rec<<<NBLK, 256, 0, stream>>>(xg, w_hh, b_hh, lengths, hbuf, flags);
  gru_out<<<BATCH, 64, 0, stream>>>(hbuf, lengths, w_out, b_out, outp);
}

// Round 6
// 3002.119 us; speedup vs baseline: 1.6377x; 1.6377x over previous
//
#include <hip/hip_runtime.h>

// ---------------------------------------------------------------------------
// SimpleGRU on MI355X (gfx950). Round 6: sentinel-ring dataflow recurrence.
//   Round-4 (PASS, 4.72ms): flag protocol at L3 scope -> 9.2us/step, chain =
//     store-ack -> flag-store -> 128-wave flag-poll tail -> data-load.
//   Round-5 (HANG): XCD-local sc0-only coherence assumption failed.
//   Now: NO flags, NO barriers, NO co-residency requirement. h(t) goes to a
//   step-indexed ring slot pre-filled with f16 sentinel 0xFFFF (NaN; real h
//   has |h|<=1, can never encode it). Each 16B chunk: one producer store
//   (fire-and-forget, sc0 sc1), one consumer lane that polls the chunk itself
//   until non-sentinel -> detection IS the data load. Strictly-backward deps
//   -> deadlock-free under any block schedule. Ring depth adapts to ws_size
//   (512 => no slot reuse; else >=16 with slack-guarded progress check).
// ws: xg bf16 [512][1536][64] (100,663,296 B) | ring [depth][64][512] f16
//     (depth*65,536 B) | prog int[128]
// ---------------------------------------------------------------------------

typedef unsigned short ushort_t;
typedef short short8      __attribute__((ext_vector_type(8)));
typedef float floatx4     __attribute__((ext_vector_type(4)));
typedef unsigned int uintx4 __attribute__((ext_vector_type(4)));
typedef unsigned short ushort4v __attribute__((ext_vector_type(4)));
typedef _Float16 half8    __attribute__((ext_vector_type(8)));

#define SEQL 512
#define BATCH 64
#define EMBD 256
#define HID 512
#define G3 1536
#define NOUT 5
#define NBLK 32
#define SLOT_BYTES 65536           // one h snapshot: 64 x 512 x 2B
#define XG_BYTES 100663296

__device__ __forceinline__ float bf2f(ushort_t v){
  union { unsigned u; float f; } x; x.u = ((unsigned)v) << 16; return x.f;
}
__device__ __forceinline__ ushort_t f2bf(float f){
  unsigned u = __float_as_uint(f);
  return (ushort_t)((u + 0x7FFFu + ((u >> 16) & 1u)) >> 16);
}
__device__ __forceinline__ float sigm(float x){
  x = fminf(fmaxf(x, -20.f), 20.f);
  return 1.f / (1.f + __expf(-x));
}
__device__ __forceinline__ float tanh_c(float x){
  x = fminf(fmaxf(x, -10.f), 10.f);
  float e = __expf(2.f * x);
  return (e - 1.f) / (e + 1.f);
}
__device__ __forceinline__ bool has_sent(half8 v){
  union { half8 h; unsigned u[4]; } x; x.h = v;
  bool b = false;
  #pragma unroll
  for (int i = 0; i < 4; ++i){
    b |= ((x.u[i] & 0xFFFFu) == 0xFFFFu);
    b |= ((x.u[i] >> 16) == 0xFFFFu);
  }
  return b;
}

// --- K0: fill ring with sentinel 0xFFFF halves; zero prog[128] ---
__global__ __launch_bounds__(256) void gru_init(uintx4* __restrict__ ring16,
                                                int* __restrict__ prog){
  size_t i = (size_t)blockIdx.x * 256 + threadIdx.x;  // grid = depth*16 blocks
  uintx4 s = {0xFFFFFFFFu, 0xFFFFFFFFu, 0xFFFFFFFFu, 0xFFFFFFFFu};
  ring16[i] = s;
  if (i < 128) prog[i] = 0;
}

// --- K1: x_gates = emb[seq] @ w_ih^T + b_ih, bf16, layout [s][1536][64] ---
#define LDSIDX2(row, chunk) (((row) << 7) + ((((chunk) ^ ((row) & 7))) << 3))
__global__ __launch_bounds__(256) void gru_xgates(
    const int* __restrict__ seq, const float* __restrict__ emb,
    const float* __restrict__ w_ih, const float* __restrict__ b_ih,
    ushort_t* __restrict__ xg)
{
  __shared__ __align__(16) short lA[64 * 128];
  __shared__ __align__(16) short lB[64 * 128];
  const int tid   = threadIdx.x;
  const int sIdx  = blockIdx.x;
  const int nBase = blockIdx.y * 64;
  const int w    = tid >> 6;
  const int l    = tid & 63;
  const int l15  = l & 15;
  const int quad = l >> 4;
  floatx4 acc[4] = {};

  #pragma unroll
  for (int kp = 0; kp < 2; ++kp){
    __syncthreads();
    #pragma unroll
    for (int i = 0; i < 4; ++i){
      int lin = i * 256 + tid;
      int row = lin >> 4;
      int kc  = lin & 15;
      int kbase = kp * 128 + kc * 8;
      int token = seq[(sIdx << 6) + row];
      const float* srcA = emb  + (size_t)token * EMBD + kbase;
      const float* srcB = w_ih + (size_t)(nBase + row) * EMBD + kbase;
      floatx4 a0 = *(const floatx4*)(srcA);
      floatx4 a1 = *(const floatx4*)(srcA + 4);
      floatx4 b0 = *(const floatx4*)(srcB);
      floatx4 b1 = *(const floatx4*)(srcB + 4);
      short8 pa, pb;
      #pragma unroll
      for (int j = 0; j < 4; ++j){
        pa[j]     = (short)f2bf(a0[j]);
        pa[j + 4] = (short)f2bf(a1[j]);
        pb[j]     = (short)f2bf(b0[j]);
        pb[j + 4] = (short)f2bf(b1[j]);
      }
      *(short8*)&lA[LDSIDX2(row, kc)] = pa;
      *(short8*)&lB[LDSIDX2(row, kc)] = pb;
    }
    __syncthreads();
    #pragma unroll
    for (int kc = 0; kc < 4; ++kc){
      int chunk = kc * 4 + quad;
      short8 a = *(const short8*)&lA[LDSIDX2(w * 16 + l15, chunk)];
      #pragma unroll
      for (int s = 0; s < 4; ++s){
        short8 bf = *(const short8*)&lB[LDSIDX2(s * 16 + l15, chunk)];
        acc[s] = __builtin_amdgcn_mfma_f32_16x16x32_bf16(a, bf, acc[s], 0, 0, 0);
      }
    }
  }
  #pragma unroll
  for (int s = 0; s < 4; ++s){
    int g = nBase + s * 16 + l15;
    float bias = b_ih[g];
    ushort4v pk;
    #pragma unroll
    for (int r = 0; r < 4; ++r) pk[r] = f2bf(acc[s][r] + bias);
    *(ushort4v*)(xg + ((size_t)sIdx * G3 + g) * BATCH + (w * 16 + quad * 4)) = pk;
  }
}

// --- K2: dataflow recurrence. 32 blocks x 256 threads, no inter-block sync
//     primitives at all — just the sentinel ring. ---
__global__ __launch_bounds__(256, 1) void gru_rec(
    const ushort_t* __restrict__ xg, const float* __restrict__ whh,
    const float* __restrict__ bhh, const int* __restrict__ lengths,
    char* __restrict__ ring, int* __restrict__ prog, int depth)
{
  __shared__ __align__(16) _Float16 wlds[48 * 64 * 8];   // 49,152 B (B-frags)
  __shared__ __align__(16) _Float16 hscr[4 * 256];       //  2,048 B (repack)
  const int g    = blockIdx.x;          // hidden slice [g*16, g*16+16)
  const int tid  = threadIdx.x;
  const int w    = tid >> 6;
  const int l    = tid & 63;
  const int l15  = l & 15;
  const int quad = l >> 4;
  const int j    = g * 16 + l15;        // this lane's hidden unit
  const int bbase = w * 16 + quad * 4;  // this lane's 4 batches

  // ---- setup: 48 W_hh rows f32->f16 into B-frag LDS layout (round-4-proven) ----
  #pragma unroll
  for (int i = 0; i < 12; ++i){
    int p  = i * 4 + w;                 // 0..47
    int G  = p >> 4;                    // gate (0=r,1=z,2=n)
    int ks = p & 15;                    // K-step
    const float* src = whh + (size_t)(G * HID + j) * HID + ks * 32 + quad * 8;
    floatx4 f0 = *(const floatx4*)(src);
    floatx4 f1 = *(const floatx4*)(src + 4);
    half8 hv;
    #pragma unroll
    for (int q = 0; q < 4; ++q){ hv[q] = (_Float16)f0[q]; hv[q + 4] = (_Float16)f1[q]; }
    *(half8*)&wlds[((size_t)p * 64 + l) * 8] = hv;
  }
  const float bhR = bhh[j], bhZ = bhh[HID + j], bhN = bhh[2 * HID + j];
  int   len[4];
  float h[4];
  #pragma unroll
  for (int r = 0; r < 4; ++r){ len[r] = lengths[bbase + r]; h[r] = 0.f; }
  const int Lmax  = lengths[0];         // sorted descending
  const int mask  = depth - 1;
  const bool reuse = (depth < Lmax);    // slot reuse only if ring shorter than seq
  int cmin = 0;
  __syncthreads();                      // wlds ready; no barriers in the loop

  for (int t = 0; t < Lmax; ++t){
    // 0) ring-reuse guard (off critical path when depth >= Lmax)
    if (reuse && t >= depth){
      int target = t - depth + 2;       // consumers must have completed this many steps
      if (cmin < target){
        int tgt2 = target + 4;          // slack; publishes every 8 guarantee progress
        while (true){
          int p0, p1;
          asm volatile("global_load_dword %0, %2, off sc0 sc1\n\t"
                       "global_load_dword %1, %3, off sc0 sc1\n\t"
                       "s_waitcnt vmcnt(0)"
                       : "=v"(p0), "=v"(p1) : "v"(prog + l), "v"(prog + 64 + l)
                       : "memory");
          if (__all(p0 >= tgt2 && p1 >= tgt2)) break;
        }
        cmin = tgt2;
      }
    }

    // 1) xg prefetch (independent of h)
    const ushort_t* xt = xg + (size_t)t * G3 * BATCH;
    ushort4v xR = __builtin_nontemporal_load(
        (const ushort4v*)(xt + (size_t)(        j) * BATCH + bbase));
    ushort4v xZ = __builtin_nontemporal_load(
        (const ushort4v*)(xt + (size_t)(HID   + j) * BATCH + bbase));
    ushort4v xN = __builtin_nontemporal_load(
        (const ushort4v*)(xt + (size_t)(2*HID + j) * BATCH + bbase));

    // 2) consume h(t-1): poll own A-chunks until non-sentinel, then MFMA
    floatx4 aR = {0.f,0.f,0.f,0.f}, aZ = {0.f,0.f,0.f,0.f}, aN = {0.f,0.f,0.f,0.f};
    if (t > 0){
      const char* rowp = ring + (size_t)((t - 1) & mask) * SLOT_BYTES
                       + (size_t)(w * 16 + l15) * 1024 + quad * 16;
      half8 aF[16];
      while (true){
        #pragma unroll
        for (int ks = 0; ks < 16; ++ks){
          const char* pa = rowp + ks * 64;
          asm volatile("global_load_dwordx4 %0, %1, off sc0 sc1"
                       : "=v"(aF[ks]) : "v"(pa) : "memory");
        }
        asm volatile("s_waitcnt vmcnt(0)"
                     : "+v"(aF[0]),  "+v"(aF[1]),  "+v"(aF[2]),  "+v"(aF[3]),
                       "+v"(aF[4]),  "+v"(aF[5]),  "+v"(aF[6]),  "+v"(aF[7]),
                       "+v"(aF[8]),  "+v"(aF[9]),  "+v"(aF[10]), "+v"(aF[11]),
                       "+v"(aF[12]), "+v"(aF[13]), "+v"(aF[14]), "+v"(aF[15])
                     :: "memory");
        bool bad = false;
        #pragma unroll
        for (int ks = 0; ks < 16; ++ks) bad |= has_sent(aF[ks]);
        if (!__any(bad)) break;
      }
      #pragma unroll
      for (int ks = 0; ks < 16; ++ks){
        half8 a  = aF[ks];
        half8 b0 = *(const half8*)&wlds[((size_t)(0 * 16 + ks) * 64 + l) * 8];
        half8 b1 = *(const half8*)&wlds[((size_t)(1 * 16 + ks) * 64 + l) * 8];
        half8 b2 = *(const half8*)&wlds[((size_t)(2 * 16 + ks) * 64 + l) * 8];
        aR = __builtin_amdgcn_mfma_f32_16x16x32_f16(a, b0, aR, 0, 0, 0);
        aZ = __builtin_amdgcn_mfma_f32_16x16x32_f16(a, b1, aZ, 0, 0, 0);
        aN = __builtin_amdgcn_mfma_f32_16x16x32_f16(a, b2, aN, 0, 0, 0);
      }
      // restore sentinel on consumed chunks so the slot can be reused
      if (reuse){
        uintx4 sv = {0xFFFFFFFFu, 0xFFFFFFFFu, 0xFFFFFFFFu, 0xFFFFFFFFu};
        #pragma unroll
        for (int ks = 0; ks < 16; ++ks){
          const char* pa = rowp + ks * 64;
          asm volatile("global_store_dwordx4 %0, %1, off sc0 sc1"
                       :: "v"(pa), "v"(sv) : "memory");
        }
      }
    }

    // 3) gates + h update (f32 carry)
    #pragma unroll
    for (int r = 0; r < 4; ++r){
      float rr = sigm(bf2f(xR[r]) + aR[r] + bhR);
      float zz = sigm(bf2f(xZ[r]) + aZ[r] + bhZ);
      float nn = tanh_c(bf2f(xN[r]) + rr * (aN[r] + bhN));
      float hn = (1.f - zz) * nn + zz * h[r];
      h[r] = (t < len[r]) ? hn : h[r];
    }

    // 4) intra-wave repack via LDS, then publish h(t) chunks (fire-and-forget)
    _Float16* scr = hscr + w * 256;
    #pragma unroll
    for (int r = 0; r < 4; ++r) scr[(quad * 4 + r) * 16 + l15] = (_Float16)h[r];
    asm volatile("s_waitcnt lgkmcnt(0)" ::: "memory");   // wave-local DS order
    if (l < 32){
      int bl = l >> 1;                  // batch-local 0..15
      int hc = l & 1;                   // which 8-wide half of the 16-slice
      half8 ch = *(const half8*)&scr[bl * 16 + hc * 8];
      const char* dst = ring + (size_t)(t & mask) * SLOT_BYTES
                      + (size_t)(w * 16 + bl) * 1024 + (size_t)(2 * g + hc) * 16;
      asm volatile("global_store_dwordx4 %0, %1, off sc0 sc1"
                   :: "v"(dst), "v"(ch) : "memory");
    }

    // 5) coarse progress publish (reuse mode only), ordered after restores
    if (reuse && ((t & 7) == 7)){
      asm volatile("s_waitcnt vmcnt(0)" ::: "memory");
      if (l == 0){
        const int* pp = prog + (w * NBLK + g);
        int pv = t + 1;
        asm volatile("global_store_dword %0, %1, off sc0 sc1"
                     :: "v"(pp), "v"(pv) : "memory");
      }
    }
  }
}

// --- K3: logits + log_softmax from ring slot (Lmax-1). 64 blocks x 64 thr. ---
__global__ __launch_bounds__(64) void gru_out(
    const char* __restrict__ ring, const int* __restrict__ lengths,
    const float* __restrict__ wout, const float* __restrict__ bout,
    float* __restrict__ out, int depth)
{
  const int b = blockIdx.x, l = threadIdx.x;
  const int Lmax = lengths[0];
  const _Float16* h = (const _Float16*)(ring
      + (size_t)((Lmax - 1) & (depth - 1)) * SLOT_BYTES + (size_t)b * 1024);
  half8 hv = *(const half8*)(h + l * 8);
  float p[NOUT];
  #pragma unroll
  for (int o = 0; o < NOUT; ++o){
    const float* wr = wout + o * HID + l * 8;
    float a = 0.f;
    #pragma unroll
    for (int i = 0; i < 8; ++i) a += wr[i] * (float)hv[i];
    #pragma unroll
    for (int d = 32; d >= 1; d >>= 1) a += __shfl_down(a, d, 64);
    p[o] = a;
  }
  if (l == 0){
    float lg[NOUT], m = -1e30f;
    #pragma unroll
    for (int o = 0; o < NOUT; ++o){
      float v = p[o] + bout[o];
      if (!(v == v)) v = -1.0f;
      lg[o] = v; m = fmaxf(m, v);
    }
    float ssum = 0.f;
    #pragma unroll
    for (int o = 0; o < NOUT; ++o) ssum += __expf(lg[o] - m);
    float ls = __logf(ssum);
    #pragma unroll
    for (int o = 0; o < NOUT; ++o) out[b * NOUT + o] = lg[o] - m - ls;
  }
}

extern "C" void kernel_launch(void* const* d_in, const int* in_sizes, int n_in,
                              void* d_out, int out_size, void* d_ws, size_t ws_size,
                              hipStream_t stream) {
  (void)in_sizes; (void)n_in; (void)out_size;
  const int*   seq     = (const int*)d_in[0];
  const int*   lengths = (const int*)d_in[1];
  const float* emb     = (const float*)d_in[2];
  const float* w_ih    = (const float*)d_in[3];
  const float* w_hh    = (const float*)d_in[4];
  const float* b_ih    = (const float*)d_in[5];
  const float* b_hh    = (const float*)d_in[6];
  const float* w_out   = (const float*)d_in[7];
  const float* b_out   = (const float*)d_in[8];
  float*       outp    = (float*)d_out;

  // ring depth: largest power of two in [16, 512] that fits the workspace.
  // (Evidence: round-3 used 102.37 MB of ws successfully -> depth>=16 fits.)
  size_t avail = (ws_size > (size_t)XG_BYTES + 1024)
               ? ws_size - (size_t)XG_BYTES - 1024 : 0;
  int depth = 16;
  while (depth < 512 && ((size_t)depth * 2 * SLOT_BYTES + 512) <= avail) depth <<= 1;

  char* ws = (char*)d_ws;
  ushort_t* xg   = (ushort_t*)ws;                                  // 100,663,296 B
  char*     ring = ws + XG_BYTES;                                  // depth*65,536 B
  int*      prog = (int*)(ws + XG_BYTES + (size_t)depth * SLOT_BYTES);

  gru_init<<<depth * 16, 256, 0, stream>>>((uintx4*)ring, prog);
  dim3 g1(SEQL, G3 / 64);
  gru_xgates<<<g1, 256, 0, stream>>>(seq, emb, w_ih, b_ih, xg);
  gru_rec<<<NBLK, 256, 0, stream>>>(xg, w_hh, b_hh, lengths, ring, prog, depth);
  gru_out<<<BATCH, 64, 0, stream>>>(ring, lengths, w_out, b_out, outp, depth);
}